// Round 1
// baseline (144.728 us; speedup 1.0000x reference)
//
#include <hip/hip_runtime.h>
#include <math.h>

// N=65536 rows, D=256 fp32. out = sum_i (counts_i - 1)*d_i + exp(d_i)
// d_i = dot(z_a[i], z_b[i]); counts_i-1 = n-3 (i < n-1), n-2 (i == n-1).
//
// R5 history: LDS-transpose reduction removed the shfl latency chain but
// stayed at ~43 us/dispatch. rocprof: VALUBusy 2.7%, hbm 19% peak,
// occupancy 17%, VGPR=52 -> latency-bound with ~2 float4 loads in flight
// (register allocator collapsed the unroll-8 load batch).
// R6: (a) explicit float4 av[8]/bv[8] register batches + sched_barrier(0)
// to force 16 outstanding dwordx4 loads per wave; (b) ROWS_PER_WAVE 32->16
// -> 1024 blocks, 16.6KB LDS, launch_bounds(256,4) -> 4 blocks/CU
// (16 waves/CU) for TLP on top of the ILP.

#define D_DIM 256
#define ROWS_PER_WAVE 16
#define WAVES_PER_BLOCK 4
#define BATCH 8
// blocks = n / (ROWS_PER_WAVE * WAVES_PER_BLOCK) = 65536/64 = 1024

__global__ __launch_bounds__(256, 4)
void dot_loss_partial(const float4* __restrict__ za4,
                      const float4* __restrict__ zb4,
                      float* __restrict__ partial,
                      int n) {
    const int lane = threadIdx.x & 63;
    const int wave = threadIdx.x >> 6;
    const int waveId = blockIdx.x * WAVES_PER_BLOCK + wave;
    const int row0 = waveId * ROWS_PER_WAVE;

    // part[wave][row][lane] stride 65: write banks (r+lane)%32 are 2-way
    // aliased; transpose-read banks (row + 16*quarter + c)%32 also exactly
    // 2-way aliased. 2-way is free on gfx950.
    __shared__ float part[WAVES_PER_BLOCK][ROWS_PER_WAVE][65];

    const float4* a = za4 + (size_t)row0 * 64 + lane;
    const float4* b = zb4 + (size_t)row0 * 64 + lane;

    // Phase 1: stream. Explicit register batch of 8 rows (a+b = 16 loads,
    // 64 VGPRs) issued before any consumption; sched_barrier(0) pins the
    // loads ahead of the fma/ds_write group so the allocator cannot
    // collapse the batch. Loads of batch 1 may hoist above batch 0's
    // consumes (both sit between the same barriers) -> up to 32 in flight.
    for (int rb = 0; rb < ROWS_PER_WAVE; rb += BATCH) {
        float4 av[BATCH], bv[BATCH];
        #pragma unroll
        for (int u = 0; u < BATCH; ++u) {
            av[u] = a[(size_t)(rb + u) * 64];
            bv[u] = b[(size_t)(rb + u) * 64];
        }
        __builtin_amdgcn_sched_barrier(0);
        #pragma unroll
        for (int u = 0; u < BATCH; ++u) {
            float t = av[u].x * bv[u].x;
            t = fmaf(av[u].y, bv[u].y, t);
            t = fmaf(av[u].z, bv[u].z, t);
            t = fmaf(av[u].w, bv[u].w, t);
            part[wave][rb + u][lane] = t;
        }
    }
    // Wave-local LDS RAW only (each wave touches its own part[wave] slab):
    // a full waitcnt is enough, no barrier needed.
    __builtin_amdgcn_s_waitcnt(0);  // vmcnt(0)+expcnt(0)+lgkmcnt(0)

    // Phase 2: transpose read. 4 lanes per row: lane j handles row (j&15),
    // columns [16*(j>>4), 16*(j>>4)+16).
    const int rowIdx = lane & 15;
    const int colBase = (lane >> 4) * 16;
    float s = 0.0f;
    #pragma unroll
    for (int c = 0; c < 16; ++c)
        s += part[wave][rowIdx][colBase + c];

    // Merge the 4 quarter-sums: lanes 0..15 end with the full dot d.
    s += __shfl_down(s, 32);
    s += __shfl_down(s, 16);

    float acc = 0.0f;
    if (lane < 16) {
        int row = row0 + rowIdx;
        float coeff = (row == n - 1) ? (float)(n - 2) : (float)(n - 3);
        acc = coeff * s + expf(s);  // 16 rows' loss terms per wave
    }

    // Reduce lanes 0..15 -> lane 0 (lanes >=16 contribute 0).
    #pragma unroll
    for (int off = 8; off > 0; off >>= 1)
        acc += __shfl_down(acc, off);

    __shared__ float smem[WAVES_PER_BLOCK];
    if (lane == 0) smem[wave] = acc;
    __syncthreads();
    if (threadIdx.x == 0) {
        float s2 = 0.0f;
        #pragma unroll
        for (int w = 0; w < WAVES_PER_BLOCK; ++w) s2 += smem[w];
        partial[blockIdx.x] = s2;
    }
}

__global__ __launch_bounds__(256)
void reduce_partials(const float* __restrict__ partial,
                     float* __restrict__ out,
                     int m) {
    const int lane = threadIdx.x & 63;
    const int wave = threadIdx.x >> 6;
    double s = 0.0;
    for (int i = threadIdx.x; i < m; i += 256)
        s += (double)partial[i];
    #pragma unroll
    for (int off = 32; off > 0; off >>= 1)
        s += __shfl_down(s, off);
    __shared__ double smem[4];
    if (lane == 0) smem[wave] = s;
    __syncthreads();
    if (threadIdx.x == 0)
        out[0] = (float)(smem[0] + smem[1] + smem[2] + smem[3]);
}

extern "C" void kernel_launch(void* const* d_in, const int* in_sizes, int n_in,
                              void* d_out, int out_size, void* d_ws, size_t ws_size,
                              hipStream_t stream) {
    const float4* za4 = (const float4*)d_in[0];
    const float4* zb4 = (const float4*)d_in[1];
    float* out = (float*)d_out;
    float* partial = (float*)d_ws;
    const int n = in_sizes[0] / D_DIM;
    const int blocks = n / (ROWS_PER_WAVE * WAVES_PER_BLOCK);  // 1024

    dot_loss_partial<<<blocks, 256, 0, stream>>>(za4, zb4, partial, n);
    reduce_partials<<<1, 256, 0, stream>>>(partial, out, blocks);
}